// Round 2
// baseline (131.614 us; speedup 1.0000x reference)
//
#include <hip/hip_runtime.h>
#include <math.h>

#define IMG   256
#define NFULL 177
#define DETN  362
#define NACQ  45
#define PAD   1024

// ws layout (floats): [0,131072) sino ; [131072,262144) sf ;
// sel table (ints) hides in sino-region spare [128160,131072);
// padded image (optional) at [262144, 262144+2*69696).
#define SINO_OFF 0
#define SF_OFF   131072
#define SEL_OFF  128160
#define PIMG_OFF 262144
#define PIMG_W   264                    // 256 + 4-px zero ring each side
#define PIMG_N   (PIMG_W * PIMG_W)      // 69696

#define TTILE  32
#define HALF_T 180.5f                   // (DETN-1)/2
// Shared tile: 5112 dwords fits 68x75, 72x71, 76x67, 80x63, 84x60.
// 5112*4 + 8 (sRange) = 20464 B -> rounds to 20480 -> 8 blocks/CU, 32 waves/CU.
#define TILE_N 5112

__constant__ const int kByOrder[12] = {5, 6, 4, 7, 3, 8, 2, 9, 1, 10, 0, 11};

// ---------------------------------------------------------------------------
// Direct HBM->LDS 16B staging (dest = wave-uniform base + lane*16; our tile
// is linear row-major with pitch == 4*W4, so float4 slot f is lane-contig).
__device__ __forceinline__ void gload16(const float* g, float* l) {
    __builtin_amdgcn_global_load_lds(
        (const __attribute__((address_space(1))) void*)g,
        (__attribute__((address_space(3))) void*)l, 16, 0, 0);
}

// ---------------------------------------------------------------------------
// Kernel 0: (a) build zero-padded image, (b) per-angle (P,L) selection.
// Selection scores predicted LDS bank multiplicity of the (tt,ts) lane
// lattice: addr deltas dT = s*P+c (per T), dS = c*P-s (per S), mod 32.
// Selection is PERFORMANCE-ONLY among candidates that pass the fit check.
__global__ __launch_bounds__(256) void prep_kernel(
    const float* __restrict__ x, const float* __restrict__ thetas,
    float* __restrict__ pimg, int* __restrict__ sel, int padded)
{
    const int tid = threadIdx.x;

    // ---- padded image: 2 * 264 * 66 = 34848 float4s over 177 blocks ----
    if (padded) {
        const int i = blockIdx.x * 256 + tid;
        const int half = PIMG_W * (PIMG_W / 4);        // 17424
        if (i < 2 * half) {
            const int b  = (i >= half) ? 1 : 0;
            const int j  = i - b * half;
            const int py = j / (PIMG_W / 4);
            const int px = (j - py * (PIMG_W / 4)) << 2;
            float4 v = make_float4(0.f, 0.f, 0.f, 0.f);
            if (py >= 4 && py < 260 && px >= 4 && px <= 256) {
                v = *(const float4*)(x + b * IMG * IMG + (py - 4) * IMG + (px - 4));
            }
            *(float4*)(pimg + b * PIMG_N + py * PIMG_W + px) = v;
        }
    }

    // ---- per-angle selection (grid.x == NFULL) ----
    __shared__ int   hist[160];
    __shared__ float cs[2];
    const int a = blockIdx.x;
    if (tid < 160) hist[tid] = 0;
    if (tid == 0) {
        const float th = thetas[a] * (float)(M_PI / 180.0);
        cs[0] = cosf(th); cs[1] = sinf(th);
    }
    __syncthreads();
    const float c = cs[0], s = cs[1];
    if (tid < 64) {
        const int tt = tid >> 3, ts = tid & 7;
        #pragma unroll
        for (int p = 0; p < 5; ++p) {
            const float P  = 68.f + 4.f * (float)p;
            const float dT = s * P + c;
            const float dS = c * P - s;
            const int bank = (int)floorf((float)tt * dT + (float)ts * dS + 0.5f) & 31;
            atomicAdd(&hist[p * 32 + bank], 1);
        }
    }
    __syncthreads();
    if (tid == 0) {
        const float ac  = fabsf(c), as = fabsf(s);
        const float sx64 = 31.f * ac + 63.f * as;   // spans of 32T x L-S window
        const float sy64 = 31.f * as + 63.f * ac;
        const float sx48 = 31.f * ac + 47.f * as;
        const float sy48 = 31.f * as + 47.f * ac;
        const int   hm[5] = {75, 71, 67, 63, 60};   // TILE_N / P
        int best = 5, bcost = 1 << 30;
        for (int p = 0; p < 5; ++p) {
            int m = 0;
            for (int k = 0; k < 32; ++k) m = max(m, hist[p * 32 + k]);
            const float Pf = 68.f + 4.f * (float)p;
            if (p < 3 && sx64 <= Pf - 8.05f && sy64 <= (float)hm[p] - 5.05f) {
                const int cst = 2 * m;
                if (cst < bcost) { bcost = cst; best = p; }
            }
            if (sx48 <= Pf - 8.05f && sy48 <= (float)hm[p] - 5.05f) {
                const int cst = 2 * m + 3;
                if (cst < bcost) { bcost = cst; best = p + 3; }
            }
        }
        sel[a] = best;   // 0..2: (68/72/76, L=64) ; 3..7: (68/72/76/80/84, L=48)
    }
}

// ---------------------------------------------------------------------------
// Radon segment loop, compile-time pitch P and segment length L.
// Staging window covers ALL 32T x L-S samples' taps (corner-extreme bounds,
// fit guaranteed by prep). Sampling loop is clipped to the WAVE's S-union
// [wlo,whi): skipped samples are exactly-zero terms (taps land in the
// zero ring), so clipping is bit-exact and cuts LDS-pipe traffic.
template<int P, int L>
__device__ __forceinline__ float radon_core(
    const float* __restrict__ img,    // unpadded (fallback)
    const float* __restrict__ pimgb,  // padded base for this batch
    float* tile, const int padded,
    const float c, const float s,
    const float xbase, const float ybase,
    const float xAB_mn, const float yAB_mn, const float yAB_mx,
    const int SloB, const int ShiB,
    const int wlo, const int whi, const int tid)
{
    constexpr int W4   = P / 4;
    constexpr int HMAX = TILE_N / P;
    const int ts   = tid & 7;
    const int wid  = tid >> 6;
    const int lane = tid & 63;
    float val = 0.0f;

    for (int Sseg = SloB; Sseg < ShiB; Sseg += L) {
        // window origin (s >= 0 for theta in [0,180))
        const float sv0 = (float)Sseg - HALF_T;
        const float sv1 = sv0 + (float)(L - 1);
        const float xmn = xAB_mn - sv1 * s;
        const float ya  = sv0 * c, yb = sv1 * c;
        const float ymn = yAB_mn + fminf(ya, yb);
        const float ymx = yAB_mx + fmaxf(ya, yb);
        const int ix0  = (int)floorf(xmn) - 1;
        const int iy0  = (int)floorf(ymn) - 1;
        const int ix0a = ix0 & ~3;
        const int h    = min((int)floorf(ymx) + 3 - iy0, HMAX);
        const int total4 = W4 * h;

        if (padded) {
            // clamp-free staging: clamped coords land in the 4-px zero ring.
            const int bx = ix0a + 4, by = iy0 + 4;
            const int nfull = total4 & ~63;
            for (int f0 = wid * 64; f0 < nfull; f0 += 256) {
                const int f  = f0 + lane;
                const int r  = f / W4;                 // compile-time magic
                const int c4 = f - r * W4;
                const int px = min(max(bx + (c4 << 2), 0), PIMG_W - 4);
                const int py = min(max(by + r, 0), PIMG_W - 1);
                gload16(pimgb + py * PIMG_W + px, tile + (f0 << 2));
            }
            const int f = nfull + tid;                 // partial-wave tail
            if (f < total4) {
                const int r  = f / W4;
                const int c4 = f - r * W4;
                const int px = min(max(bx + (c4 << 2), 0), PIMG_W - 4);
                const int py = min(max(by + r, 0), PIMG_W - 1);
                *(float4*)(tile + (f << 2)) =
                    *(const float4*)(pimgb + py * PIMG_W + px);
            }
        } else {
            // fallback: clamped+masked float4 staging from original image
            for (int f = tid; f < total4; f += 256) {
                const int r  = f / W4;
                const int c4 = f - r * W4;
                const int gy = iy0 + r;
                const int gx = ix0a + (c4 << 2);
                const int cyc = min(max(gy, 0), IMG - 1);
                const int cxc = min(max(gx, 0), IMG - 4);
                float4 v = *(const float4*)(img + cyc * IMG + cxc);
                const bool ok = ((unsigned)gy < (unsigned)IMG) &
                                ((unsigned)gx <= (unsigned)(IMG - 4));
                if (!ok) v = make_float4(0.f, 0.f, 0.f, 0.f);
                *(float4*)(tile + (f << 2)) = v;
            }
        }
        __syncthreads();

        const float xoff = xbase - (float)ix0a;
        const float yoff = ybase - (float)iy0;
        const int Send = min(Sseg + L, ShiB);
        // wave-clipped, phase-aligned bounds (never read below Sseg)
        const int SA = Sseg + (max(wlo - Sseg, 0) & ~7);
        const int SB = min(Send, whi);

        #pragma unroll 4
        for (int S = SA + ts; S < SB; S += 8) {
            const float sval = (float)S - HALF_T;
            const float xs  = fmaf(-sval, s, xoff);
            const float ys  = fmaf(sval, c, yoff);
            const float x0f = floorf(xs);
            const float y0f = floorf(ys);
            const float wx  = xs - x0f;
            const float wy  = ys - y0f;
            // base fits exactly in float (< 2^24): saves a cvt+mul
            const int base = (int)fmaf(y0f, (float)P, x0f);
            const float v00 = tile[base];
            const float v01 = tile[base + 1];       // ds_read2 (0,1)
            const float v10 = tile[base + P];
            const float v11 = tile[base + P + 1];   // ds_read2 (P,P+1)
            const float h0 = fmaf(wx, v01 - v00, v00);
            const float h1 = fmaf(wx, v11 - v10, v10);
            val += fmaf(wy, h1 - h0, h0);
        }
        __syncthreads();
        Sseg = Sseg;  // (loop var advanced by += L)
    }
    return val;
}

// ---------------------------------------------------------------------------
// Kernel A: radon. Block = (b,angle) x 32-T tile, 256 thr = 32 T x 8 S-phase.
// __launch_bounds__(256,8): cap VGPR<=64 so LDS (20464B -> 8 blocks/CU) binds.
__global__ __launch_bounds__(256, 8) void radon_kernel(
    const float* __restrict__ x, const float* __restrict__ pimg,
    const int* __restrict__ sel, const float* __restrict__ thetas,
    float* __restrict__ sino, int padded)
{
    const int blk = blockIdx.x;        // b*NFULL + a
    const int b = blk / NFULL;
    const int a = blk - b * NFULL;
    const int T0 = kByOrder[blockIdx.y] * TTILE;
    const int tid = threadIdx.x;
    const int ts = tid & 7;
    const int tt = tid >> 3;
    const int T = T0 + tt;

    __shared__ __align__(16) float tile[TILE_N];
    __shared__ int sRange[2];

    const float th = thetas[a] * (float)(M_PI / 180.0);
    const float c = cosf(th);
    const float s = sinf(th);
    const float cx = (IMG - 1) * 0.5f;
    const float cy = (IMG - 1) * 0.5f;
    const float Tc = (float)T - HALF_T;
    const float xbase = Tc * c + cx;   // xs = xbase - sval*s
    const float ybase = Tc * s + cy;   // ys = ybase + sval*c

    // per-thread valid-S clipping -> wave union (sampling) + block union
    float lo = -1e30f, hi = 1e30f;
    bool empty = (T >= DETN);
    {   const float aa = -s;
        if (aa > 1e-5f)       { lo = fmaxf(lo, (-1.0f - xbase) / aa); hi = fminf(hi, (256.0f - xbase) / aa); }
        else if (aa < -1e-5f) { lo = fmaxf(lo, (256.0f - xbase) / aa); hi = fminf(hi, (-1.0f - xbase) / aa); }
        else if (xbase <= -1.0f || xbase >= 256.0f) empty = true;
    }
    {   const float aa = c;
        if (aa > 1e-5f)       { lo = fmaxf(lo, (-1.0f - ybase) / aa); hi = fminf(hi, (256.0f - ybase) / aa); }
        else if (aa < -1e-5f) { lo = fmaxf(lo, (256.0f - ybase) / aa); hi = fminf(hi, (-1.0f - ybase) / aa); }
        else if (ybase <= -1.0f || ybase >= 256.0f) empty = true;
    }
    lo = fmaxf(lo, -200.0f);
    hi = fminf(hi, 200.0f);
    int Slo = max(0, (int)floorf(lo + HALF_T) - 1);
    int Shi = min(DETN, (int)floorf(hi + HALF_T) + 2);
    if (empty || Shi < Slo) { Slo = 0; Shi = 0; }

    if (tid == 0) { sRange[0] = DETN; sRange[1] = 0; }
    __syncthreads();
    if (Shi > Slo) { atomicMin(&sRange[0], Slo); atomicMax(&sRange[1], Shi); }

    // wave-level S-union (butterfly over 64 lanes)
    int wlo = (Shi > Slo) ? Slo : DETN;
    int whi = (Shi > Slo) ? Shi : 0;
    #pragma unroll
    for (int d = 1; d < 64; d <<= 1) {
        wlo = min(wlo, __shfl_xor(wlo, d, 64));
        whi = max(whi, __shfl_xor(whi, d, 64));
    }
    __syncthreads();
    const int SloB = sRange[0], ShiB = sRange[1];

    // hoisted tile-corner terms
    const float TcA = (float)T0 - HALF_T;
    const float TcB = (float)(T0 + TTILE - 1) - HALF_T;
    const float xAB_mn = fminf(TcA * c + cx, TcB * c + cx);
    const float yAB_mn = fminf(TcA * s + cy, TcB * s + cy);
    const float yAB_mx = fmaxf(TcA * s + cy, TcB * s + cy);

    const float* __restrict__ img   = x + b * IMG * IMG;
    const float* __restrict__ pimgb = pimg + b * PIMG_N;
    const int selv = sel[a];

    float val;
    switch (selv) {
    case 0:  val = radon_core<68,64>(img, pimgb, tile, padded, c, s, xbase, ybase,
                                     xAB_mn, yAB_mn, yAB_mx, SloB, ShiB, wlo, whi, tid); break;
    case 1:  val = radon_core<72,64>(img, pimgb, tile, padded, c, s, xbase, ybase,
                                     xAB_mn, yAB_mn, yAB_mx, SloB, ShiB, wlo, whi, tid); break;
    case 2:  val = radon_core<76,64>(img, pimgb, tile, padded, c, s, xbase, ybase,
                                     xAB_mn, yAB_mn, yAB_mx, SloB, ShiB, wlo, whi, tid); break;
    case 3:  val = radon_core<68,48>(img, pimgb, tile, padded, c, s, xbase, ybase,
                                     xAB_mn, yAB_mn, yAB_mx, SloB, ShiB, wlo, whi, tid); break;
    case 4:  val = radon_core<72,48>(img, pimgb, tile, padded, c, s, xbase, ybase,
                                     xAB_mn, yAB_mn, yAB_mx, SloB, ShiB, wlo, whi, tid); break;
    case 5:  val = radon_core<76,48>(img, pimgb, tile, padded, c, s, xbase, ybase,
                                     xAB_mn, yAB_mn, yAB_mx, SloB, ShiB, wlo, whi, tid); break;
    case 6:  val = radon_core<80,48>(img, pimgb, tile, padded, c, s, xbase, ybase,
                                     xAB_mn, yAB_mn, yAB_mx, SloB, ShiB, wlo, whi, tid); break;
    default: val = radon_core<84,48>(img, pimgb, tile, padded, c, s, xbase, ybase,
                                     xAB_mn, yAB_mn, yAB_mx, SloB, ShiB, wlo, whi, tid); break;
    }

    val += __shfl_xor(val, 1, 8);
    val += __shfl_xor(val, 2, 8);
    val += __shfl_xor(val, 4, 8);
    if (ts == 0 && T < DETN) {
        sino[(b * NFULL + a) * DETN + T] = val;
    }
}

// ---------------------------------------------------------------------------
// Kernel B: data-consistency + ramp filter (unchanged).
__global__ __launch_bounds__(192) void dc_filter_kernel(
    const float* __restrict__ sino,
    const float* __restrict__ st,
    const int*   __restrict__ acq,
    float* __restrict__ sf)
{
    const int blk = blockIdx.x;
    const int b = blk / NFULL;
    const int a = blk - b * NFULL;
    const int tid = threadIdx.x;

    __shared__ float col[DETN];
    __shared__ float gf[PAD];

    const float SC = (float)(M_PI / (2.0 * NFULL));
    const float c0 = 0.5f * SC;
    for (int n = tid; n < PAD; n += 192) {
        float v = 0.0f;
        if (n & 1) {
            const int d = (n < PAD - n) ? n : (PAD - n);
            const float pd = (float)M_PI * (float)d;
            v = -2.0f / (pd * pd) * SC;
        }
        gf[n] = v;
    }

    int inv = -1;
    for (int i = 0; i < NACQ; ++i) {
        if (acq[i] == a) inv = i;
    }

    for (int m = tid; m < DETN; m += 192) {
        float val = sino[(b * NFULL + a) * DETN + m];
        if (inv >= 0) {
            val = st[(b * DETN + m) * NACQ + inv] - val;
        }
        col[m] = val;
    }
    __syncthreads();

    const int T = blockIdx.y * 181 + tid;
    if (tid < 181) {
        const int m0 = (T + 1) & 1;
        float acc = c0 * col[T];
        #pragma unroll 4
        for (int k = 0; k < 181; ++k) {
            const int m = m0 + 2 * k;
            acc += col[m] * gf[(T - m) & (PAD - 1)];
        }
        sf[(b * NFULL + a) * DETN + T] = acc;
    }
}

// ---------------------------------------------------------------------------
// Kernel C: backprojection (unchanged).
__global__ __launch_bounds__(256) void backproject_kernel(
    const float* __restrict__ sf,
    const float* __restrict__ thetas,
    float* __restrict__ out)
{
    __shared__ float cb[2 * NFULL];
    __shared__ float red[256];
    const int tid = threadIdx.x;
    const int lane  = tid & 63;
    const int phase = tid >> 6;
    const int pix = blockIdx.x * 64 + lane;
    const int b = pix >> 16;
    const int y = (pix >> 8) & 255;
    const int xq = pix & 255;
    const float gx = (float)xq - (IMG - 1) * 0.5f;
    const float gy = (float)y  - (IMG - 1) * 0.5f;

    for (int a = tid; a < NFULL; a += 256) {
        float th = thetas[a] * (float)(M_PI / 180.0);
        cb[2 * a]     = cosf(th);
        cb[2 * a + 1] = fmaf(sinf(th), gy, HALF_T);
    }
    __syncthreads();

    const float* __restrict__ sfb = sf + b * NFULL * DETN;

    float acc = 0.0f;
    #pragma unroll 4
    for (int a = phase; a < NFULL; a += 4) {
        const float cs = cb[2 * a];
        const float bs = cb[2 * a + 1];
        const float t = fmaf(cs, gx, bs);
        const float t0f = floorf(t);
        const float w = t - t0f;
        const float* row = sfb + a * DETN + (int)t0f;
        const float v0 = row[0];
        const float v1 = row[1];
        acc += v0 + w * (v1 - v0);
    }
    red[tid] = acc;
    __syncthreads();
    if (tid < 64) {
        out[blockIdx.x * 64 + tid] =
            red[tid] + red[tid + 64] + red[tid + 128] + red[tid + 192];
    }
}

extern "C" void kernel_launch(void* const* d_in, const int* in_sizes, int n_in,
                              void* d_out, int out_size, void* d_ws, size_t ws_size,
                              hipStream_t stream) {
    const float* x      = (const float*)d_in[0];
    const float* st     = (const float*)d_in[1];
    const float* thetas = (const float*)d_in[2];
    const int*   acq    = (const int*)d_in[3];
    float* out  = (float*)d_out;
    float* wsf  = (float*)d_ws;
    float* sino = wsf + SINO_OFF;
    float* sf   = wsf + SF_OFF;
    int*   sel  = (int*)(wsf + SEL_OFF);
    float* pimg = wsf + PIMG_OFF;

    const size_t need = (size_t)(PIMG_OFF + 2 * PIMG_N) * sizeof(float);
    const int padded = (ws_size >= need) ? 1 : 0;

    prep_kernel<<<NFULL, 256, 0, stream>>>(x, thetas, pimg, sel, padded);
    dim3 gA(2 * NFULL, 12);
    radon_kernel<<<gA, 256, 0, stream>>>(x, pimg, sel, thetas, sino, padded);
    dim3 gB(2 * NFULL, 2);
    dc_filter_kernel<<<gB, 192, 0, stream>>>(sino, st, acq, sf);
    backproject_kernel<<<(2 * IMG * IMG) / 64, 256, 0, stream>>>(sf, thetas, out);
}

// Round 3
// 128.021 us; speedup vs baseline: 1.0281x; 1.0281x over previous
//
#include <hip/hip_runtime.h>
#include <math.h>

#define IMG   256
#define NFULL 177
#define DETN  362
#define NACQ  45
#define PAD   1024

// ws layout (floats): [0,131072) sino ; [131072,262144) sf
#define SINO_OFF 0
#define SF_OFF   131072

#define TTILE  32
#define HALF_T 180.5f                   // (DETN-1)/2
// Shared tile: 5112 dwords fits 68x75, 72x71, 76x67 (pitch x Hmax).
// 5112*4 + 12 (sRange+sSel) -> 20480 B LDS block -> 8 blocks/CU, 32 waves/CU.
#define TILE_N 5112

__constant__ const int kByOrder[12] = {5, 6, 4, 7, 3, 8, 2, 9, 1, 10, 0, 11};

// ---------------------------------------------------------------------------
// Direct HBM->LDS 16B staging (dest = wave-uniform base + lane*16; our tile
// is linear row-major with pitch == 4*W4, so float4 slot f is lane-contig).
__device__ __forceinline__ void gload16(const float* g, float* l) {
    __builtin_amdgcn_global_load_lds(
        (const __attribute__((address_space(1))) void*)g,
        (__attribute__((address_space(3))) void*)l, 16, 0, 0);
}

// ---------------------------------------------------------------------------
// Radon segment loop, compile-time pitch P and segment length L (R1 form).
// Staging window covers ALL 32T x L-S samples' taps (corner-extreme bounds,
// fit guaranteed by the inline selection). Hybrid staging: wave-uniform
// interior chunks go HBM->LDS direct; boundary chunks use masked float4.
template<int P, int L>
__device__ __forceinline__ float radon_core(
    const float* __restrict__ img,
    float* tile,
    const float c, const float s,
    const float xbase, const float ybase,
    const float xAB_mn, const float yAB_mn, const float yAB_mx,
    const int SloB, const int ShiB, const int tid)
{
    constexpr int W4   = P / 4;
    constexpr int HMAX = TILE_N / P;
    const int ts   = tid & 7;
    const int wid  = tid >> 6;
    const int lane = tid & 63;
    float val = 0.0f;

    for (int Sseg = SloB; Sseg < ShiB; Sseg += L) {
        // window origin (s >= 0 for theta in [0,180))
        const float sv0 = (float)Sseg - HALF_T;
        const float sv1 = sv0 + (float)(L - 1);
        const float xmn = xAB_mn - sv1 * s;
        const float ya  = sv0 * c, yb = sv1 * c;
        const float ymn = yAB_mn + fminf(ya, yb);
        const float ymx = yAB_mx + fmaxf(ya, yb);
        const int ix0  = (int)floorf(xmn) - 1;
        const int iy0  = (int)floorf(ymn) - 1;
        const int ix0a = ix0 & ~3;
        const int h    = min((int)floorf(ymx) + 3 - iy0, HMAX);
        const int total4 = W4 * h;

        // ---- hybrid staging straight from the original image ----
        // gx is 4-aligned and IMG%4==0 -> per-float4 validity all-or-nothing.
        const int nfull = total4 & ~63;
        for (int f0 = wid * 64; f0 < nfull; f0 += 256) {
            const int f  = f0 + lane;
            const int r  = f / W4;                 // compile-time magic
            const int c4 = f - r * W4;
            const int gy = iy0 + r;
            const int gx = ix0a + (c4 << 2);
            const bool ok = ((unsigned)gy < (unsigned)IMG) &
                            ((unsigned)gx <= (unsigned)(IMG - 4));
            if (__all(ok)) {
                gload16(img + gy * IMG + gx, tile + (f0 << 2));
            } else {
                float4 v = make_float4(0.f, 0.f, 0.f, 0.f);
                if (ok) v = *(const float4*)(img + gy * IMG + gx);
                *(float4*)(tile + (f << 2)) = v;
            }
        }
        {   // tail (<64 float4s): per-lane masked
            const int f = nfull + tid;
            if (f < total4) {
                const int r  = f / W4;
                const int c4 = f - r * W4;
                const int gy = iy0 + r;
                const int gx = ix0a + (c4 << 2);
                const bool ok = ((unsigned)gy < (unsigned)IMG) &
                                ((unsigned)gx <= (unsigned)(IMG - 4));
                float4 v = make_float4(0.f, 0.f, 0.f, 0.f);
                if (ok) v = *(const float4*)(img + gy * IMG + gx);
                *(float4*)(tile + (f << 2)) = v;
            }
        }
        __syncthreads();

        const float xoff = xbase - (float)ix0a;
        const float yoff = ybase - (float)iy0;
        const int Send = min(Sseg + L, ShiB);

        auto samp = [&](float sval) {
            const float xs  = fmaf(-sval, s, xoff);
            const float ys  = fmaf(sval, c, yoff);
            const float x0f = floorf(xs);
            const float y0f = floorf(ys);
            const float wx  = xs - x0f;
            const float wy  = ys - y0f;
            // base fits exactly in float (< 2^24): saves a cvt+mul
            const int base = (int)fmaf(y0f, (float)P, x0f);
            const float v00 = tile[base];
            const float v01 = tile[base + 1];       // ds_read2 (0,1)
            const float v10 = tile[base + P];
            const float v11 = tile[base + P + 1];   // ds_read2 (P,P+1)
            const float h0 = fmaf(wx, v01 - v00, v00);
            const float h1 = fmaf(wx, v11 - v10, v10);
            val += fmaf(wy, h1 - h0, h0);
        };

        if (Send - Sseg == L) {
            // fast path: compile-time trip count
            const float s0 = (float)(Sseg + ts) - HALF_T;
            #pragma unroll 4
            for (int u = 0; u < L / 8; ++u) samp(s0 + (float)(8 * u));
        } else {
            for (int S = Sseg + ts; S < Send; S += 8) samp((float)S - HALF_T);
        }
        __syncthreads();
    }
    return val;
}

// ---------------------------------------------------------------------------
// Kernel A: radon. Block = (b,angle) x 32-T tile, 256 thr = 32 T x 8 S-phase.
// __launch_bounds__(256,8): cap VGPR<=64 so LDS (20480B -> 8 blocks/CU) binds.
// (P,L) selection is inlined (wave 0, ballot-based bank-multiplicity score,
// identical candidate set + cost model to the R1 prep kernel) -> no prep
// dispatch. Selection is PERFORMANCE-ONLY among fit-checked candidates.
__global__ __launch_bounds__(256, 8) void radon_kernel(
    const float* __restrict__ x,
    const float* __restrict__ thetas,
    float* __restrict__ sino)
{
    const int blk = blockIdx.x;        // b*NFULL + a
    const int b = blk / NFULL;
    const int a = blk - b * NFULL;
    const int T0 = kByOrder[blockIdx.y] * TTILE;
    const int tid = threadIdx.x;
    const int ts = tid & 7;
    const int tt = tid >> 3;
    const int T = T0 + tt;

    __shared__ __align__(16) float tile[TILE_N];
    __shared__ int sRange[2];
    __shared__ int sSel;

    const float th = thetas[a] * (float)(M_PI / 180.0);
    const float c = cosf(th);
    const float s = sinf(th);
    const float cx = (IMG - 1) * 0.5f;
    const float cy = (IMG - 1) * 0.5f;
    const float Tc = (float)T - HALF_T;
    const float xbase = Tc * c + cx;   // xs = xbase - sval*s
    const float ybase = Tc * s + cy;   // ys = ybase + sval*c

    // per-thread valid-S clipping -> block union
    float lo = -1e30f, hi = 1e30f;
    bool empty = (T >= DETN);
    {   const float aa = -s;
        if (aa > 1e-5f)       { lo = fmaxf(lo, (-1.0f - xbase) / aa); hi = fminf(hi, (256.0f - xbase) / aa); }
        else if (aa < -1e-5f) { lo = fmaxf(lo, (256.0f - xbase) / aa); hi = fminf(hi, (-1.0f - xbase) / aa); }
        else if (xbase <= -1.0f || xbase >= 256.0f) empty = true;
    }
    {   const float aa = c;
        if (aa > 1e-5f)       { lo = fmaxf(lo, (-1.0f - ybase) / aa); hi = fminf(hi, (256.0f - ybase) / aa); }
        else if (aa < -1e-5f) { lo = fmaxf(lo, (256.0f - ybase) / aa); hi = fminf(hi, (-1.0f - ybase) / aa); }
        else if (ybase <= -1.0f || ybase >= 256.0f) empty = true;
    }
    lo = fmaxf(lo, -200.0f);
    hi = fminf(hi, 200.0f);
    int Slo = max(0, (int)floorf(lo + HALF_T) - 1);
    int Shi = min(DETN, (int)floorf(hi + HALF_T) + 2);
    if (empty || Shi < Slo) { Slo = 0; Shi = 0; }

    if (tid == 0) { sRange[0] = DETN; sRange[1] = 0; }
    __syncthreads();
    if (Shi > Slo) { atomicMin(&sRange[0], Slo); atomicMax(&sRange[1], Shi); }

    // inline (P,L) selection on wave 0 (piggybacks on the sRange barriers).
    // Bank model: lane (ltt,lts) reads at addr ~ ltt*dT + lts*dS, dT=s*P+c,
    // dS=c*P-s; multiplicity via 5-bit ballot match + popcount, wave-max.
    if (tid < 64) {
        const int ltt = tid >> 3, lts = tid & 7;
        const float ac = fabsf(c), as = fabsf(s);
        const float spx = 31.f * ac + 63.f * as;   // spans of 32T x 64S window
        const float spy = 31.f * as + 63.f * ac;
        const int hm[3] = {75, 71, 67};            // TILE_N / P
        int best = 5, bcost = 1 << 30;
        #pragma unroll
        for (int p = 0; p < 3; ++p) {
            const float Pf = 68.f + 4.f * (float)p;
            const float dT = s * Pf + c;
            const float dS = c * Pf - s;
            const int bank = (int)floorf((float)ltt * dT + (float)lts * dS + 0.5f) & 31;
            unsigned long long m = ~0ull;
            #pragma unroll
            for (int bit = 0; bit < 5; ++bit) {
                const unsigned long long bb = __ballot((bank >> bit) & 1);
                m &= ((bank >> bit) & 1) ? bb : ~bb;
            }
            int cnt = __popcll(m);
            #pragma unroll
            for (int d = 1; d < 64; d <<= 1) cnt = max(cnt, __shfl_xor(cnt, d, 64));
            if (spx <= Pf - 8.05f && spy <= (float)hm[p] - 5.05f) {
                if (2 * cnt < bcost) { bcost = 2 * cnt; best = p; }
            }
            // L=48 always fits for P in {68,72,76} (span <= 56.3)
            if (2 * cnt + 3 < bcost) { bcost = 2 * cnt + 3; best = p + 3; }
        }
        if (tid == 0) sSel = best;
    }
    __syncthreads();
    const int SloB = sRange[0], ShiB = sRange[1];
    const int selv = sSel;

    // hoisted tile-corner terms
    const float TcA = (float)T0 - HALF_T;
    const float TcB = (float)(T0 + TTILE - 1) - HALF_T;
    const float xAB_mn = fminf(TcA * c + cx, TcB * c + cx);
    const float yAB_mn = fminf(TcA * s + cy, TcB * s + cy);
    const float yAB_mx = fmaxf(TcA * s + cy, TcB * s + cy);

    const float* __restrict__ img = x + b * IMG * IMG;

    float val;
    switch (selv) {
    case 0:  val = radon_core<68,64>(img, tile, c, s, xbase, ybase,
                                     xAB_mn, yAB_mn, yAB_mx, SloB, ShiB, tid); break;
    case 1:  val = radon_core<72,64>(img, tile, c, s, xbase, ybase,
                                     xAB_mn, yAB_mn, yAB_mx, SloB, ShiB, tid); break;
    case 2:  val = radon_core<76,64>(img, tile, c, s, xbase, ybase,
                                     xAB_mn, yAB_mn, yAB_mx, SloB, ShiB, tid); break;
    case 3:  val = radon_core<68,48>(img, tile, c, s, xbase, ybase,
                                     xAB_mn, yAB_mn, yAB_mx, SloB, ShiB, tid); break;
    case 4:  val = radon_core<72,48>(img, tile, c, s, xbase, ybase,
                                     xAB_mn, yAB_mn, yAB_mx, SloB, ShiB, tid); break;
    default: val = radon_core<76,48>(img, tile, c, s, xbase, ybase,
                                     xAB_mn, yAB_mn, yAB_mx, SloB, ShiB, tid); break;
    }

    val += __shfl_xor(val, 1, 8);
    val += __shfl_xor(val, 2, 8);
    val += __shfl_xor(val, 4, 8);
    if (ts == 0 && T < DETN) {
        sino[(b * NFULL + a) * DETN + T] = val;
    }
}

// ---------------------------------------------------------------------------
// Kernel B: data-consistency + ramp filter (unchanged).
__global__ __launch_bounds__(192) void dc_filter_kernel(
    const float* __restrict__ sino,
    const float* __restrict__ st,
    const int*   __restrict__ acq,
    float* __restrict__ sf)
{
    const int blk = blockIdx.x;
    const int b = blk / NFULL;
    const int a = blk - b * NFULL;
    const int tid = threadIdx.x;

    __shared__ float col[DETN];
    __shared__ float gf[PAD];

    const float SC = (float)(M_PI / (2.0 * NFULL));
    const float c0 = 0.5f * SC;
    for (int n = tid; n < PAD; n += 192) {
        float v = 0.0f;
        if (n & 1) {
            const int d = (n < PAD - n) ? n : (PAD - n);
            const float pd = (float)M_PI * (float)d;
            v = -2.0f / (pd * pd) * SC;
        }
        gf[n] = v;
    }

    int inv = -1;
    for (int i = 0; i < NACQ; ++i) {
        if (acq[i] == a) inv = i;
    }

    for (int m = tid; m < DETN; m += 192) {
        float val = sino[(b * NFULL + a) * DETN + m];
        if (inv >= 0) {
            val = st[(b * DETN + m) * NACQ + inv] - val;
        }
        col[m] = val;
    }
    __syncthreads();

    const int T = blockIdx.y * 181 + tid;
    if (tid < 181) {
        const int m0 = (T + 1) & 1;
        float acc = c0 * col[T];
        #pragma unroll 4
        for (int k = 0; k < 181; ++k) {
            const int m = m0 + 2 * k;
            acc += col[m] * gf[(T - m) & (PAD - 1)];
        }
        sf[(b * NFULL + a) * DETN + T] = acc;
    }
}

// ---------------------------------------------------------------------------
// Kernel C: backprojection (unchanged).
__global__ __launch_bounds__(256) void backproject_kernel(
    const float* __restrict__ sf,
    const float* __restrict__ thetas,
    float* __restrict__ out)
{
    __shared__ float cb[2 * NFULL];
    __shared__ float red[256];
    const int tid = threadIdx.x;
    const int lane  = tid & 63;
    const int phase = tid >> 6;
    const int pix = blockIdx.x * 64 + lane;
    const int b = pix >> 16;
    const int y = (pix >> 8) & 255;
    const int xq = pix & 255;
    const float gx = (float)xq - (IMG - 1) * 0.5f;
    const float gy = (float)y  - (IMG - 1) * 0.5f;

    for (int a = tid; a < NFULL; a += 256) {
        float th = thetas[a] * (float)(M_PI / 180.0);
        cb[2 * a]     = cosf(th);
        cb[2 * a + 1] = fmaf(sinf(th), gy, HALF_T);
    }
    __syncthreads();

    const float* __restrict__ sfb = sf + b * NFULL * DETN;

    float acc = 0.0f;
    #pragma unroll 4
    for (int a = phase; a < NFULL; a += 4) {
        const float cs = cb[2 * a];
        const float bs = cb[2 * a + 1];
        const float t = fmaf(cs, gx, bs);
        const float t0f = floorf(t);
        const float w = t - t0f;
        const float* row = sfb + a * DETN + (int)t0f;
        const float v0 = row[0];
        const float v1 = row[1];
        acc += v0 + w * (v1 - v0);
    }
    red[tid] = acc;
    __syncthreads();
    if (tid < 64) {
        out[blockIdx.x * 64 + tid] =
            red[tid] + red[tid + 64] + red[tid + 128] + red[tid + 192];
    }
}

extern "C" void kernel_launch(void* const* d_in, const int* in_sizes, int n_in,
                              void* d_out, int out_size, void* d_ws, size_t ws_size,
                              hipStream_t stream) {
    const float* x      = (const float*)d_in[0];
    const float* st     = (const float*)d_in[1];
    const float* thetas = (const float*)d_in[2];
    const int*   acq    = (const int*)d_in[3];
    float* out  = (float*)d_out;
    float* wsf  = (float*)d_ws;
    float* sino = wsf + SINO_OFF;
    float* sf   = wsf + SF_OFF;

    dim3 gA(2 * NFULL, 12);
    radon_kernel<<<gA, 256, 0, stream>>>(x, thetas, sino);
    dim3 gB(2 * NFULL, 2);
    dc_filter_kernel<<<gB, 192, 0, stream>>>(sino, st, acq, sf);
    backproject_kernel<<<(2 * IMG * IMG) / 64, 256, 0, stream>>>(sf, thetas, out);
}

// Round 4
// 126.105 us; speedup vs baseline: 1.0437x; 1.0152x over previous
//
#include <hip/hip_runtime.h>
#include <math.h>

#define IMG   256
#define NFULL 177
#define DETN  362
#define NACQ  45
#define PAD   1024

// ws layout (floats): [0,131072) sino ; [131072,262144) sf
#define SINO_OFF 0
#define SF_OFF   131072

#define TTILE  32
#define HALF_T 180.5f                   // (DETN-1)/2
// Shared tile: 5112 dwords fits 68x75, 72x71, 76x67 (pitch x Hmax).
// 5112*4 + 12 (sRange+sSel) -> 20480 B LDS block -> 8 blocks/CU, 32 waves/CU.
#define TILE_N 5112

__constant__ const int kByOrder[12] = {5, 6, 4, 7, 3, 8, 2, 9, 1, 10, 0, 11};

// ---------------------------------------------------------------------------
// Direct HBM->LDS 16B staging (dest = wave-uniform base + lane*16; our tile
// is linear row-major with pitch == 4*W4, so float4 slot f is lane-contig).
__device__ __forceinline__ void gload16(const float* g, float* l) {
    __builtin_amdgcn_global_load_lds(
        (const __attribute__((address_space(1))) void*)g,
        (__attribute__((address_space(3))) void*)l, 16, 0, 0);
}

// ---------------------------------------------------------------------------
// Radon segment loop, compile-time pitch P and segment length L.
// Staging window covers ALL 32T x L-S samples' taps (corner-extreme bounds,
// fit guaranteed by the inline selection). Interior/boundary decision is
// SEGMENT-level (wave-uniform): interior -> clamp-free gload16 stream;
// boundary -> masked float4 (every cell written, OOB cells exact zeros).
template<int P, int L>
__device__ __forceinline__ float radon_core(
    const float* __restrict__ img,
    float* tile,
    const float c, const float s,
    const float xbase, const float ybase,
    const float xAB_mn, const float yAB_mn, const float yAB_mx,
    const int SloB, const int ShiB, const int tid)
{
    constexpr int W4   = P / 4;
    constexpr int HMAX = TILE_N / P;
    const int ts   = tid & 7;
    const int wid  = tid >> 6;
    const int lane = tid & 63;
    float val = 0.0f;

    for (int Sseg = SloB; Sseg < ShiB; Sseg += L) {
        // window origin (s >= 0 for theta in [0,180))
        const float sv0 = (float)Sseg - HALF_T;
        const float sv1 = sv0 + (float)(L - 1);
        const float xmn = xAB_mn - sv1 * s;
        const float ya  = sv0 * c, yb = sv1 * c;
        const float ymn = yAB_mn + fminf(ya, yb);
        const float ymx = yAB_mx + fmaxf(ya, yb);
        const int ix0  = (int)floorf(xmn) - 1;
        const int iy0  = (int)floorf(ymn) - 1;
        const int ix0a = ix0 & ~3;
        const int h    = min((int)floorf(ymx) + 3 - iy0, HMAX);
        const int total4 = W4 * h;

        // staged cells cover exactly [ix0a, ix0a+P) x [iy0, iy0+h)
        const bool interior = (ix0a >= 0) & (iy0 >= 0) &
                              (ix0a + P <= IMG) & (iy0 + h <= IMG);
        if (interior) {
            // clamp-free, predicate-free HBM->LDS stream (common case)
            const float* __restrict__ src = img + iy0 * IMG + ix0a;
            for (int f0 = wid * 64; f0 < total4; f0 += 256) {
                const int f = f0 + lane;
                if (f < total4) {                      // exec-masked ragged tail
                    const int r  = f / W4;             // compile-time magic
                    const int c4 = f - r * W4;
                    gload16(src + r * IMG + (c4 << 2), tile + (f0 << 2));
                }
            }
        } else {
            // boundary: masked float4 (gx 4-aligned, IMG%4==0 -> all-or-nothing)
            for (int f = tid; f < total4; f += 256) {
                const int r  = f / W4;
                const int c4 = f - r * W4;
                const int gy = iy0 + r;
                const int gx = ix0a + (c4 << 2);
                const bool ok = ((unsigned)gy < (unsigned)IMG) &
                                ((unsigned)gx <= (unsigned)(IMG - 4));
                float4 v = make_float4(0.f, 0.f, 0.f, 0.f);
                if (ok) v = *(const float4*)(img + gy * IMG + gx);
                *(float4*)(tile + (f << 2)) = v;
            }
        }
        __syncthreads();

        const float xoff = xbase - (float)ix0a;
        const float yoff = ybase - (float)iy0;
        const int Send = min(Sseg + L, ShiB);

        auto samp = [&](float sval) {
            const float xs  = fmaf(-sval, s, xoff);
            const float ys  = fmaf(sval, c, yoff);
            const float x0f = floorf(xs);
            const float y0f = floorf(ys);
            const float wx  = xs - x0f;
            const float wy  = ys - y0f;
            // base fits exactly in float (< 2^24): saves a cvt+mul
            const int base = (int)fmaf(y0f, (float)P, x0f);
            const float v00 = tile[base];
            const float v01 = tile[base + 1];       // ds_read2 (0,1)
            const float v10 = tile[base + P];
            const float v11 = tile[base + P + 1];   // ds_read2 (P,P+1)
            const float h0 = fmaf(wx, v01 - v00, v00);
            const float h1 = fmaf(wx, v11 - v10, v10);
            val += fmaf(wy, h1 - h0, h0);
        };

        if (Send - Sseg == L) {
            // fast path: compile-time trip count
            const float s0 = (float)(Sseg + ts) - HALF_T;
            #pragma unroll 4
            for (int u = 0; u < L / 8; ++u) samp(s0 + (float)(8 * u));
        } else {
            for (int S = Sseg + ts; S < Send; S += 8) samp((float)S - HALF_T);
        }
        __syncthreads();
    }
    return val;
}

// ---------------------------------------------------------------------------
// Kernel A: radon. Block = (b,angle) x 32-T tile, 256 thr = 32 T x 8 S-phase.
// __launch_bounds__(256,8): cap VGPR<=64 so LDS (20480B -> 8 blocks/CU) binds.
// (P,L) selection inlined on wave 0 (ballot-based bank-multiplicity score,
// candidate set + cost model identical to the R1 prep kernel).
__global__ __launch_bounds__(256, 8) void radon_kernel(
    const float* __restrict__ x,
    const float* __restrict__ thetas,
    float* __restrict__ sino)
{
    const int blk = blockIdx.x;        // b*NFULL + a
    const int b = blk / NFULL;
    const int a = blk - b * NFULL;
    const int T0 = kByOrder[blockIdx.y] * TTILE;
    const int tid = threadIdx.x;
    const int ts = tid & 7;
    const int tt = tid >> 3;
    const int T = T0 + tt;

    __shared__ __align__(16) float tile[TILE_N];
    __shared__ int sRange[2];
    __shared__ int sSel;

    const float th = thetas[a] * (float)(M_PI / 180.0);
    const float c = cosf(th);
    const float s = sinf(th);
    const float cx = (IMG - 1) * 0.5f;
    const float cy = (IMG - 1) * 0.5f;
    const float Tc = (float)T - HALF_T;
    const float xbase = Tc * c + cx;   // xs = xbase - sval*s
    const float ybase = Tc * s + cy;   // ys = ybase + sval*c

    // per-thread valid-S clipping -> block union
    float lo = -1e30f, hi = 1e30f;
    bool empty = (T >= DETN);
    {   const float aa = -s;
        if (aa > 1e-5f)       { lo = fmaxf(lo, (-1.0f - xbase) / aa); hi = fminf(hi, (256.0f - xbase) / aa); }
        else if (aa < -1e-5f) { lo = fmaxf(lo, (256.0f - xbase) / aa); hi = fminf(hi, (-1.0f - xbase) / aa); }
        else if (xbase <= -1.0f || xbase >= 256.0f) empty = true;
    }
    {   const float aa = c;
        if (aa > 1e-5f)       { lo = fmaxf(lo, (-1.0f - ybase) / aa); hi = fminf(hi, (256.0f - ybase) / aa); }
        else if (aa < -1e-5f) { lo = fmaxf(lo, (256.0f - ybase) / aa); hi = fminf(hi, (-1.0f - ybase) / aa); }
        else if (ybase <= -1.0f || ybase >= 256.0f) empty = true;
    }
    lo = fmaxf(lo, -200.0f);
    hi = fminf(hi, 200.0f);
    int Slo = max(0, (int)floorf(lo + HALF_T) - 1);
    int Shi = min(DETN, (int)floorf(hi + HALF_T) + 2);
    if (empty || Shi < Slo) { Slo = 0; Shi = 0; }

    if (tid == 0) { sRange[0] = DETN; sRange[1] = 0; }
    __syncthreads();
    if (Shi > Slo) { atomicMin(&sRange[0], Slo); atomicMax(&sRange[1], Shi); }

    // inline (P,L) selection on wave 0 (piggybacks on the sRange barriers).
    // Bank model: lane (ltt,lts) reads at addr ~ ltt*dT + lts*dS, dT=s*P+c,
    // dS=c*P-s; multiplicity via 5-bit ballot match + popcount, wave-max.
    if (tid < 64) {
        const int ltt = tid >> 3, lts = tid & 7;
        const float ac = fabsf(c), as = fabsf(s);
        const float spx = 31.f * ac + 63.f * as;   // spans of 32T x 64S window
        const float spy = 31.f * as + 63.f * ac;
        const int hm[3] = {75, 71, 67};            // TILE_N / P
        int best = 5, bcost = 1 << 30;
        #pragma unroll
        for (int p = 0; p < 3; ++p) {
            const float Pf = 68.f + 4.f * (float)p;
            const float dT = s * Pf + c;
            const float dS = c * Pf - s;
            const int bank = (int)floorf((float)ltt * dT + (float)lts * dS + 0.5f) & 31;
            unsigned long long m = ~0ull;
            #pragma unroll
            for (int bit = 0; bit < 5; ++bit) {
                const unsigned long long bb = __ballot((bank >> bit) & 1);
                m &= ((bank >> bit) & 1) ? bb : ~bb;
            }
            int cnt = __popcll(m);
            #pragma unroll
            for (int d = 1; d < 64; d <<= 1) cnt = max(cnt, __shfl_xor(cnt, d, 64));
            if (spx <= Pf - 8.05f && spy <= (float)hm[p] - 5.05f) {
                if (2 * cnt < bcost) { bcost = 2 * cnt; best = p; }
            }
            // L=48 always fits for P in {68,72,76} (span <= 56.3)
            if (2 * cnt + 3 < bcost) { bcost = 2 * cnt + 3; best = p + 3; }
        }
        if (tid == 0) sSel = best;
    }
    __syncthreads();
    const int SloB = sRange[0], ShiB = sRange[1];
    const int selv = sSel;

    // hoisted tile-corner terms
    const float TcA = (float)T0 - HALF_T;
    const float TcB = (float)(T0 + TTILE - 1) - HALF_T;
    const float xAB_mn = fminf(TcA * c + cx, TcB * c + cx);
    const float yAB_mn = fminf(TcA * s + cy, TcB * s + cy);
    const float yAB_mx = fmaxf(TcA * s + cy, TcB * s + cy);

    const float* __restrict__ img = x + b * IMG * IMG;

    float val;
    switch (selv) {
    case 0:  val = radon_core<68,64>(img, tile, c, s, xbase, ybase,
                                     xAB_mn, yAB_mn, yAB_mx, SloB, ShiB, tid); break;
    case 1:  val = radon_core<72,64>(img, tile, c, s, xbase, ybase,
                                     xAB_mn, yAB_mn, yAB_mx, SloB, ShiB, tid); break;
    case 2:  val = radon_core<76,64>(img, tile, c, s, xbase, ybase,
                                     xAB_mn, yAB_mn, yAB_mx, SloB, ShiB, tid); break;
    case 3:  val = radon_core<68,48>(img, tile, c, s, xbase, ybase,
                                     xAB_mn, yAB_mn, yAB_mx, SloB, ShiB, tid); break;
    case 4:  val = radon_core<72,48>(img, tile, c, s, xbase, ybase,
                                     xAB_mn, yAB_mn, yAB_mx, SloB, ShiB, tid); break;
    default: val = radon_core<76,48>(img, tile, c, s, xbase, ybase,
                                     xAB_mn, yAB_mn, yAB_mx, SloB, ShiB, tid); break;
    }

    val += __shfl_xor(val, 1, 8);
    val += __shfl_xor(val, 2, 8);
    val += __shfl_xor(val, 4, 8);
    if (ts == 0 && T < DETN) {
        sino[(b * NFULL + a) * DETN + T] = val;
    }
}

// ---------------------------------------------------------------------------
// Kernel B: data-consistency + ramp filter (unchanged).
__global__ __launch_bounds__(192) void dc_filter_kernel(
    const float* __restrict__ sino,
    const float* __restrict__ st,
    const int*   __restrict__ acq,
    float* __restrict__ sf)
{
    const int blk = blockIdx.x;
    const int b = blk / NFULL;
    const int a = blk - b * NFULL;
    const int tid = threadIdx.x;

    __shared__ float col[DETN];
    __shared__ float gf[PAD];

    const float SC = (float)(M_PI / (2.0 * NFULL));
    const float c0 = 0.5f * SC;
    for (int n = tid; n < PAD; n += 192) {
        float v = 0.0f;
        if (n & 1) {
            const int d = (n < PAD - n) ? n : (PAD - n);
            const float pd = (float)M_PI * (float)d;
            v = -2.0f / (pd * pd) * SC;
        }
        gf[n] = v;
    }

    int inv = -1;
    for (int i = 0; i < NACQ; ++i) {
        if (acq[i] == a) inv = i;
    }

    for (int m = tid; m < DETN; m += 192) {
        float val = sino[(b * NFULL + a) * DETN + m];
        if (inv >= 0) {
            val = st[(b * DETN + m) * NACQ + inv] - val;
        }
        col[m] = val;
    }
    __syncthreads();

    const int T = blockIdx.y * 181 + tid;
    if (tid < 181) {
        const int m0 = (T + 1) & 1;
        float acc = c0 * col[T];
        #pragma unroll 4
        for (int k = 0; k < 181; ++k) {
            const int m = m0 + 2 * k;
            acc += col[m] * gf[(T - m) & (PAD - 1)];
        }
        sf[(b * NFULL + a) * DETN + T] = acc;
    }
}

// ---------------------------------------------------------------------------
// Kernel C: backprojection (unchanged).
__global__ __launch_bounds__(256) void backproject_kernel(
    const float* __restrict__ sf,
    const float* __restrict__ thetas,
    float* __restrict__ out)
{
    __shared__ float cb[2 * NFULL];
    __shared__ float red[256];
    const int tid = threadIdx.x;
    const int lane  = tid & 63;
    const int phase = tid >> 6;
    const int pix = blockIdx.x * 64 + lane;
    const int b = pix >> 16;
    const int y = (pix >> 8) & 255;
    const int xq = pix & 255;
    const float gx = (float)xq - (IMG - 1) * 0.5f;
    const float gy = (float)y  - (IMG - 1) * 0.5f;

    for (int a = tid; a < NFULL; a += 256) {
        float th = thetas[a] * (float)(M_PI / 180.0);
        cb[2 * a]     = cosf(th);
        cb[2 * a + 1] = fmaf(sinf(th), gy, HALF_T);
    }
    __syncthreads();

    const float* __restrict__ sfb = sf + b * NFULL * DETN;

    float acc = 0.0f;
    #pragma unroll 4
    for (int a = phase; a < NFULL; a += 4) {
        const float cs = cb[2 * a];
        const float bs = cb[2 * a + 1];
        const float t = fmaf(cs, gx, bs);
        const float t0f = floorf(t);
        const float w = t - t0f;
        const float* row = sfb + a * DETN + (int)t0f;
        const float v0 = row[0];
        const float v1 = row[1];
        acc += v0 + w * (v1 - v0);
    }
    red[tid] = acc;
    __syncthreads();
    if (tid < 64) {
        out[blockIdx.x * 64 + tid] =
            red[tid] + red[tid + 64] + red[tid + 128] + red[tid + 192];
    }
}

extern "C" void kernel_launch(void* const* d_in, const int* in_sizes, int n_in,
                              void* d_out, int out_size, void* d_ws, size_t ws_size,
                              hipStream_t stream) {
    const float* x      = (const float*)d_in[0];
    const float* st     = (const float*)d_in[1];
    const float* thetas = (const float*)d_in[2];
    const int*   acq    = (const int*)d_in[3];
    float* out  = (float*)d_out;
    float* wsf  = (float*)d_ws;
    float* sino = wsf + SINO_OFF;
    float* sf   = wsf + SF_OFF;

    dim3 gA(2 * NFULL, 12);
    radon_kernel<<<gA, 256, 0, stream>>>(x, thetas, sino);
    dim3 gB(2 * NFULL, 2);
    dc_filter_kernel<<<gB, 192, 0, stream>>>(sino, st, acq, sf);
    backproject_kernel<<<(2 * IMG * IMG) / 64, 256, 0, stream>>>(sf, thetas, out);
}